// Round 13
// baseline (110.101 us; speedup 1.0000x reference)
//
#include <hip/hip_runtime.h>
#include <stdint.h>

// VectorQuantizer on MI355X (gfx950), round 13: bf16x3 split MFMA, de-stalled.
// R12 evidence: MFMA busy ~9.5us (at floor) but kernel 45us -- ~28us stall.
// Causes: (a) 12-deep serial MFMA chains (2 chains/wave x 2 waves/SIMD can't
// cover ~20cy MFMA latency); (b) A-intro reads x at lane-stride 256B (64-line
// gather per float4). Fixes: split each 6-term chain into two independent
// 3-term chains (T1,T4,T5 | T2,T3,T6; fp32 add at end) -> 4 chains/wave;
// stage x through LDS coalesced (reuse B buffer, +4 row pad, 2-way max).
// Geometry and bench-verified A/B/C fragment mappings unchanged from R12.

#define DDIM 64
#define KCODES 512

typedef __bf16 bf16x8 __attribute__((ext_vector_type(8)));
typedef float f32x4 __attribute__((ext_vector_type(4)));

// ws layout (bytes): WB @0 (196608), wT @196608 (131072), wsq @327680 (2048)

__device__ __forceinline__ void split3(float f, __bf16& h1, __bf16& h2,
                                       __bf16& h3) {
  h1 = (__bf16)f;
  float r1 = f - (float)h1;   // exact (Sterbenz)
  h2 = (__bf16)r1;
  float r2 = r1 - (float)h2;  // exact
  h3 = (__bf16)r2;            // residual beyond h3 ~ 2^-27 |f|
}

__global__ void vq_prep_m(const float* __restrict__ w,
                          bf16x8* __restrict__ wb,   // [3][32*2*64]
                          float* __restrict__ wT, float* __restrict__ wsq,
                          float* __restrict__ loss_out) {
  const int b = blockIdx.x, t = threadIdx.x;
  if (b < 16) {
    // ---- w split -> B-fragment layout: chunk id c = (ctg*2+h)*64 + L ----
    const int c = b * 256 + t;                // 0..4095
    const int ctg = c >> 7;                   // 16-code tile 0..31
    const int h = (c >> 6) & 1;               // k-half
    const int L = c & 63, quad = L >> 4, col = L & 15;
    bf16x8 v1, v2, v3;
#pragma unroll
    for (int j = 0; j < 8; ++j) {
      // B[k=quad*8+32h+j][n=ctg*16+col]  (R11/R12 bench-verified)
      float f = w[(quad * 8 + 32 * h + j) * KCODES + ctg * 16 + col];
      __bf16 h1, h2, h3; split3(f, h1, h2, h3);
      v1[j] = h1; v2[j] = h2; v3[j] = h3;
    }
    wb[c] = v1; wb[4096 + c] = v2; wb[8192 + c] = v3;
  } else {
    // ---- wT transpose + wsq + loss zero ----
    int g = (b - 16) * 256 + t;               // 0..32767 over D*K
    int d = g >> 9, k = g & 511;
    wT[k * DDIM + d] = w[g];
    if (g < KCODES) {
      float s = 0.f;
      for (int dd = 0; dd < DDIM; ++dd) {
        float tv = w[dd * KCODES + g];
        s = fmaf(tv, tv, s);
      }
      wsq[g] = s;
    }
    if (g == 0) *loss_out = 0.f;              // d_out is poisoned each launch
  }
}

__global__ __launch_bounds__(256, 2)
void vq_mfma(const float* __restrict__ x_in, const bf16x8* __restrict__ wb,
             const float* __restrict__ wsq, const float* __restrict__ wT,
             float* __restrict__ out_q, float* __restrict__ out_idx,
             float* __restrict__ loss_out) {
  // union: x-stage tile (128 x 68 floats = 34816 B) then B phases (48 KB)
  __shared__ char smem_raw[49152];
  bf16x8* ldsb = (bf16x8*)smem_raw;
  float (*xs)[68] = (float(*)[68])smem_raw;   // +4 pad: 2-way max bank alias
  __shared__ unsigned long long sm_key[128];
  __shared__ float sm_xsq[128];
  __shared__ unsigned int sm_idx[128];
  __shared__ float sm_loss[128];

  const int t = threadIdx.x, b = blockIdx.x;  // 512 blocks, 128 pts each
  const int wv = t >> 6, L = t & 63, quad = L >> 4, col = L & 15;

  // ---- stage 128 pts x 64 dims coalesced into padded LDS ----
  {
    const float4* xsrc = (const float4*)(x_in + (size_t)b * 8192);
#pragma unroll
    for (int i = 0; i < 8; ++i) {
      int e4 = i * 256 + t;                   // 0..2047
      float4 v = xsrc[e4];                    // coalesced 16B/lane
      int pt = e4 >> 4, d4 = e4 & 15;
      *(float4*)&xs[pt][d4 * 4] = v;
    }
  }
  __syncthreads();

  // ---- build A-fragments from LDS (conflict-light b128 reads) ----
  // a[as][split][h]; lane holds A[m=col][k=quad*8+32h+j] of point
  // pt(block-local) = (wv*2+as)*16 + col   (R11/R12 bench-verified)
  bf16x8 a[2][3][2];
#pragma unroll
  for (int as = 0; as < 2; ++as) {
    const int pt = (wv * 2 + as) * 16 + col;
    float ssq = 0.f;
#pragma unroll
    for (int h = 0; h < 2; ++h) {
      float4 p0 = *(const float4*)&xs[pt][quad * 8 + 32 * h];
      float4 p1 = *(const float4*)&xs[pt][quad * 8 + 32 * h + 4];
      float f[8] = {p0.x, p0.y, p0.z, p0.w, p1.x, p1.y, p1.z, p1.w};
      bf16x8 v1, v2, v3;
#pragma unroll
      for (int j = 0; j < 8; ++j) {
        ssq = fmaf(f[j], f[j], ssq);
        __bf16 h1, h2, h3; split3(f[j], h1, h2, h3);
        v1[j] = h1; v2[j] = h2; v3[j] = h3;
      }
      a[as][0][h] = v1; a[as][1][h] = v2; a[as][2][h] = v3;
    }
    ssq += __shfl_xor(ssq, 16, 64);           // combine the 4 quads
    ssq += __shfl_xor(ssq, 32, 64);
    if (quad == 0) sm_xsq[wv * 32 + as * 16 + col] = ssq;  // fp32-exact
  }

  float best[2][4];
  int bidx[2][4];
#pragma unroll
  for (int as = 0; as < 2; ++as)
#pragma unroll
    for (int r = 0; r < 4; ++r) { best[as][r] = 3.0e38f; bidx[as][r] = 0; }

#pragma unroll 1
  for (int ph = 0; ph < 4; ++ph) {
    __syncthreads();                          // x-reads / prev compute done
    // stage 48 chunks (ct,h,s) x 64 lanes of B-frags into LDS
#pragma unroll
    for (int i = 0; i < 12; ++i) {
      int idx = i * 256 + t;
      int chunk = idx >> 6, Ls = idx & 63;    // chunk = ct*6 + h*3 + s
      int ct = chunk / 6, r6 = chunk % 6;
      int h = r6 / 3, s = r6 % 3;
      ldsb[chunk * 64 + Ls] = wb[s * 4096 + ((ph * 8 + ct) * 2 + h) * 64 + Ls];
    }
    __syncthreads();
#pragma unroll 1
    for (int ct = 0; ct < 8; ++ct) {
      // 4 independent chains: (a-set 0/1) x (chain A: T1,T4,T5 | B: T2,T3,T6)
      f32x4 aA0 = {0.f, 0.f, 0.f, 0.f}, aB0 = {0.f, 0.f, 0.f, 0.f};
      f32x4 aA1 = {0.f, 0.f, 0.f, 0.f}, aB1 = {0.f, 0.f, 0.f, 0.f};
#pragma unroll
      for (int h = 0; h < 2; ++h) {
        bf16x8 b0 = ldsb[(ct * 6 + h * 3 + 0) * 64 + L];
        bf16x8 b1 = ldsb[(ct * 6 + h * 3 + 1) * 64 + L];
        bf16x8 b2 = ldsb[(ct * 6 + h * 3 + 2) * 64 + L];
        aA0 = __builtin_amdgcn_mfma_f32_16x16x32_bf16(a[0][0][h], b0, aA0, 0, 0, 0); // x1w1
        aB0 = __builtin_amdgcn_mfma_f32_16x16x32_bf16(a[0][0][h], b1, aB0, 0, 0, 0); // x1w2
        aA1 = __builtin_amdgcn_mfma_f32_16x16x32_bf16(a[1][0][h], b0, aA1, 0, 0, 0);
        aB1 = __builtin_amdgcn_mfma_f32_16x16x32_bf16(a[1][0][h], b1, aB1, 0, 0, 0);
        aB0 = __builtin_amdgcn_mfma_f32_16x16x32_bf16(a[0][1][h], b0, aB0, 0, 0, 0); // x2w1
        aA0 = __builtin_amdgcn_mfma_f32_16x16x32_bf16(a[0][1][h], b1, aA0, 0, 0, 0); // x2w2
        aB1 = __builtin_amdgcn_mfma_f32_16x16x32_bf16(a[1][1][h], b0, aB1, 0, 0, 0);
        aA1 = __builtin_amdgcn_mfma_f32_16x16x32_bf16(a[1][1][h], b1, aA1, 0, 0, 0);
        aA0 = __builtin_amdgcn_mfma_f32_16x16x32_bf16(a[0][0][h], b2, aA0, 0, 0, 0); // x1w3
        aB0 = __builtin_amdgcn_mfma_f32_16x16x32_bf16(a[0][2][h], b0, aB0, 0, 0, 0); // x3w1
        aA1 = __builtin_amdgcn_mfma_f32_16x16x32_bf16(a[1][0][h], b2, aA1, 0, 0, 0);
        aB1 = __builtin_amdgcn_mfma_f32_16x16x32_bf16(a[1][2][h], b0, aB1, 0, 0, 0);
      }
      f32x4 acc0 = aA0 + aB0;
      f32x4 acc1 = aA1 + aB1;
      // dist + per-lane argmin; C layout: pt = quad*4 + r, code = col
      int code = ph * 128 + ct * 16 + col;
      float wq = wsq[code];
#pragma unroll
      for (int r = 0; r < 4; ++r) {
        float d0 = fmaf(acc0[r], -2.0f, wq);
        if (d0 < best[0][r]) { best[0][r] = d0; bidx[0][r] = code; }
        float d1 = fmaf(acc1[r], -2.0f, wq);
        if (d1 < best[1][r]) { best[1][r] = d1; bidx[1][r] = code; }
      }
    }
  }

  // ---- cross-lane reduce over the 16 cols; idx in low bits -> lowest idx ----
#pragma unroll
  for (int as = 0; as < 2; ++as) {
#pragma unroll
    for (int r = 0; r < 4; ++r) {
      unsigned int ub = __float_as_uint(best[as][r]);
      ub = (ub & 0x80000000u) ? ~ub : (ub | 0x80000000u);
      unsigned long long key = ((unsigned long long)ub << 32) |
                               (unsigned long long)(unsigned int)bidx[as][r];
#pragma unroll
      for (int off = 1; off < 16; off <<= 1) {
        unsigned long long o = __shfl_xor(key, off, 64);
        key = o < key ? o : key;
      }
      if (col == 0)
        sm_key[wv * 32 + as * 16 + quad * 4 + r] = key;
    }
  }
  __syncthreads();

  if (t < 128) {
    unsigned long long k = sm_key[t];
    unsigned int idx = (unsigned int)k;
    sm_idx[t] = idx;
    out_idx[(size_t)b * 128 + t] = (float)idx;
    unsigned int u = (unsigned int)(k >> 32);
    u = (u & 0x80000000u) ? (u & 0x7FFFFFFFu) : ~u;
    // ||x-q||^2 = ||x||^2 + (||q||^2 - 2 x.q), pre-scaled by 1.25/(N*D)
    sm_loss[t] = (__uint_as_float(u) + sm_xsq[t]) * (1.25f / 4194304.0f);
  }
  __syncthreads();

  // ---- fused epilogue: gather code rows, coalesced 128x64 out tile ----
  float4* dst = (float4*)(out_q + (size_t)b * 8192);
#pragma unroll
  for (int i = 0; i < 8; ++i) {
    int e4 = i * 256 + t;
    int p2 = e4 >> 4, d4 = e4 & 15;
    unsigned int idx = sm_idx[p2];                            // LDS broadcast
    dst[e4] = ((const float4*)(wT + (size_t)idx * DDIM))[d4]; // L2-hot
  }

  if (t < 64) {
    float s = sm_loss[t] + sm_loss[t + 64];
#pragma unroll
    for (int off = 32; off > 0; off >>= 1) s += __shfl_down(s, off);
    if (t == 0) atomicAdd(loss_out, s);       // 512 adds total
  }
}

// ---------------- fallback (R9 kernels, proven) ----------------

__global__ void vq_prep(const float* __restrict__ w, float* __restrict__ wT,
                        float* __restrict__ wsq, float* __restrict__ loss_out) {
  int g = blockIdx.x * 256 + threadIdx.x;
  int d = g >> 9, k = g & 511;
  wT[k * DDIM + d] = w[g];
  if (g < KCODES) {
    float s = 0.f;
    for (int dd = 0; dd < DDIM; ++dd) {
      float t = w[dd * KCODES + g];
      s = fmaf(t, t, s);
    }
    wsq[g] = s;
  }
  if (g == 0) *loss_out = 0.f;
}

__global__ __launch_bounds__(512, 8)
void vq_main(const float* __restrict__ x_in, const float* __restrict__ w,
             const float* __restrict__ wT, const float* __restrict__ wsq,
             float* __restrict__ out_q, float* __restrict__ out_idx,
             float* __restrict__ loss_out) {
  __shared__ float xs[DDIM][65];
  __shared__ unsigned long long sm_key[8][64];
  __shared__ unsigned int sm_idx[64];
  __shared__ float sm_sx[64];
  __shared__ float sm_loss[64];

  const int t = threadIdx.x;
  const int pb = blockIdx.x;
  const int wv = __builtin_amdgcn_readfirstlane(t >> 6);
  const int lane = t & 63;

  {
    const float4* src = (const float4*)(x_in + (size_t)pb * 4096);
#pragma unroll
    for (int i = 0; i < 2; ++i) {
      int e4 = i * 512 + t;
      float4 v = src[e4];
      int e = e4 << 2;
      int pt = e >> 6, d = e & 63;
      xs[d][pt] = v.x; xs[d + 1][pt] = v.y;
      xs[d + 2][pt] = v.z; xs[d + 3][pt] = v.w;
    }
  }
  __syncthreads();

  const int kbase = wv << 6;
  float best = 3.0e38f;
  int bidx = 0;
  float sx = 0.f;

#pragma unroll 1
  for (int kb = 0; kb < 2; ++kb) {
    const int k0 = kbase + (kb << 5);
    const float* wp = w + k0;
    float acc[32];
#pragma unroll
    for (int c = 0; c < 32; ++c) acc[c] = 0.f;
#pragma unroll 1
    for (int d8 = 0; d8 < 8; ++d8) {
      float xv[8];
#pragma unroll
      for (int dd = 0; dd < 8; ++dd) xv[dd] = xs[(d8 << 3) + dd][lane];
      if (wv == 0 && kb == 0) {
#pragma unroll
        for (int dd = 0; dd < 8; ++dd) sx = fmaf(xv[dd], xv[dd], sx);
      }
#pragma unroll
      for (int dd = 0; dd < 8; ++dd) {
        const float* wd = wp + (((d8 << 3) + dd) << 9);
#pragma unroll
        for (int c = 0; c < 32; ++c) acc[c] = fmaf(wd[c], xv[dd], acc[c]);
      }
    }
#pragma unroll
    for (int c = 0; c < 32; ++c) {
      float dist = fmaf(acc[c], -2.0f, wsq[k0 + c]);
      if (dist < best) { best = dist; bidx = k0 + c; }
    }
  }

  unsigned int ub = __float_as_uint(best);
  ub = (ub & 0x80000000u) ? ~ub : (ub | 0x80000000u);
  sm_key[wv][lane] =
      ((unsigned long long)ub << 32) | (unsigned long long)(unsigned int)bidx;
  if (wv == 0) sm_sx[lane] = sx;
  __syncthreads();

  if (t < 64) {
    unsigned long long k = sm_key[0][t];
#pragma unroll
    for (int wi = 1; wi < 8; ++wi) {
      unsigned long long k2 = sm_key[wi][t];
      k = k2 < k ? k2 : k;
    }
    unsigned int idx = (unsigned int)k;
    sm_idx[t] = idx;
    out_idx[((size_t)pb << 6) + t] = (float)idx;
    unsigned int u = (unsigned int)(k >> 32);
    u = (u & 0x80000000u) ? (u & 0x7FFFFFFFu) : ~u;
    sm_loss[t] = (__uint_as_float(u) + sm_sx[t]) * (1.25f / 4194304.0f);
  }
  __syncthreads();

  float4* dst = (float4*)(out_q + (size_t)pb * 4096);
#pragma unroll
  for (int i = 0; i < 2; ++i) {
    int e4 = i * 512 + t;
    int p2 = e4 >> 4, d4 = e4 & 15;
    unsigned int idx = sm_idx[p2];
    dst[e4] = ((const float4*)(wT + (size_t)idx * DDIM))[d4];
  }

  if (t < 64) {
    float s = sm_loss[t];
#pragma unroll
    for (int off = 32; off > 0; off >>= 1) s += __shfl_down(s, off);
    if (t == 0) atomicAdd(loss_out, s);
  }
}

extern "C" void kernel_launch(void* const* d_in, const int* in_sizes, int n_in,
                              void* d_out, int out_size, void* d_ws, size_t ws_size,
                              hipStream_t stream) {
  const float* x = (const float*)d_in[0];  // (64,32,32,64) fp32
  const float* w = (const float*)d_in[1];  // (64,512) fp32

  float* out_q = (float*)d_out;            // 4194304 floats
  float* out_idx = out_q + 4194304;        // 65536 floats (indices)
  float* loss_out = out_q + 4259840;       // 1 float

  char* ws = (char*)d_ws;
  if (ws_size >= 329728) {
    bf16x8* wbp = (bf16x8*)(ws);
    float* wT = (float*)(ws + 196608);
    float* wsq = (float*)(ws + 327680);
    vq_prep_m<<<144, 256, 0, stream>>>(w, wbp, wT, wsq, loss_out);
    vq_mfma<<<512, 256, 0, stream>>>(x, wbp, wsq, wT, out_q, out_idx,
                                     loss_out);
  } else {
    float* wT = (float*)(ws);
    float* wsq = (float*)(ws + 131072);
    vq_prep<<<128, 256, 0, stream>>>(w, wT, wsq, loss_out);
    vq_main<<<1024, 512, 0, stream>>>(x, w, wT, wsq, out_q, out_idx,
                                      loss_out);
  }
}